// Round 1
// baseline (6314.879 us; speedup 1.0000x reference)
//
#include <hip/hip_runtime.h>

typedef unsigned int uintt;

__device__ __forceinline__ unsigned fkey(float f) {
  unsigned u = __float_as_uint(f);
  return (u & 0x80000000u) ? ~u : (u | 0x80000000u);
}
__device__ __forceinline__ float funkey(unsigned k) {
  unsigned u = (k & 0x80000000u) ? (k ^ 0x80000000u) : ~k;
  return __uint_as_float(u);
}

// ---------------- weight pad: lin_w (193x128) -> wpad (196x128, rows 193..195 zero)
__global__ __launch_bounds__(256) void k_wpad(const float* __restrict__ lin_w,
                                              float* __restrict__ wpad) {
  int idx = blockIdx.x * 256 + threadIdx.x;
  if (idx >= 196 * 128) return;
  int r = idx >> 7;
  wpad[idx] = (r < 193) ? lin_w[idx] : 0.f;
}

// ---------------- CSR build ----------------
__global__ __launch_bounds__(256) void k_count(const int* __restrict__ dst,
                                               int* __restrict__ counts, int E) {
  int e = blockIdx.x * 256 + threadIdx.x;
  if (e < E) atomicAdd(&counts[dst[e]], 1);
}

__global__ __launch_bounds__(256) void k_scan1(const int* __restrict__ counts,
                                               int* __restrict__ offsets,
                                               int* __restrict__ blockSums, int N) {
  __shared__ int sm[256];
  int tid = threadIdx.x;
  int gid = blockIdx.x * 256 + tid;
  int v = (gid < N) ? counts[gid] : 0;
  sm[tid] = v;
  __syncthreads();
  for (int off = 1; off < 256; off <<= 1) {
    int t = (tid >= off) ? sm[tid - off] : 0;
    __syncthreads();
    sm[tid] += t;
    __syncthreads();
  }
  if (gid < N) offsets[gid] = sm[tid] - v;  // exclusive within block
  if (tid == 255) blockSums[blockIdx.x] = sm[255];
}

__global__ __launch_bounds__(1024) void k_scan2(int* __restrict__ blockSums, int NB) {
  __shared__ int sm[1024];
  int tid = threadIdx.x;
  int v = (tid < NB) ? blockSums[tid] : 0;
  sm[tid] = v;
  __syncthreads();
  for (int off = 1; off < 1024; off <<= 1) {
    int t = (tid >= off) ? sm[tid - off] : 0;
    __syncthreads();
    sm[tid] += t;
    __syncthreads();
  }
  if (tid < NB) blockSums[tid] = sm[tid] - v;  // exclusive
}

__global__ __launch_bounds__(256) void k_scan3(const int* __restrict__ counts,
                                               int* __restrict__ offsets,
                                               const int* __restrict__ blockSums,
                                               int* __restrict__ fillpos,
                                               float* __restrict__ deginv, int N, int E) {
  int gid = blockIdx.x * 256 + threadIdx.x;
  if (gid < N) {
    int off = offsets[gid] + blockSums[gid >> 8];
    offsets[gid] = off;
    fillpos[gid] = off;
    deginv[gid] = 1.f / fmaxf((float)counts[gid], 1.f);
  }
  if (gid == 0) offsets[N] = E;
}

__global__ __launch_bounds__(256) void k_fill(const int* __restrict__ src,
                                              const int* __restrict__ dst,
                                              int* __restrict__ fillpos,
                                              int* __restrict__ esrc, int E) {
  int e = blockIdx.x * 256 + threadIdx.x;
  if (e < E) {
    int p = atomicAdd(&fillpos[dst[e]], 1);
    esrc[p] = src[e];
  }
}

// ---------------- encode: gather/concat features + relu(x @ wpad + b) ----------------
// block = 256 threads, 64 nodes/block; 4 threads per node, 32 cols each (NC=128)
__global__ __launch_bounds__(256) void k_encode(
    const float* __restrict__ node_feat, const float* __restrict__ cfgf,
    const int* __restrict__ opcode, const float* __restrict__ op_emb,
    const float* __restrict__ type_emb, const float* __restrict__ wpad,
    const float* __restrict__ bias, float* __restrict__ Out, int N) {
  constexpr int K = 196, KP = 200, NC = 128, CPT = 32;
  __shared__ float smem[64 * KP];
  const int base = blockIdx.x * 64;
  // stage concatenated rows: [feat 0..138 | type_emb 4 | op_emb 32 | cfg 18 | 0 pad 3]
  for (int idx = threadIdx.x; idx < 64 * K; idx += 256) {
    int r = idx / K, c = idx - r * K;
    int n = base + r;
    float v = 0.f;
    if (n < N) {
      if (c < 139) {
        v = node_feat[(size_t)n * 140 + c];
      } else if (c < 143) {
        int ty = (int)node_feat[(size_t)n * 140 + 139];
        v = type_emb[ty * 4 + (c - 139)];
      } else if (c < 175) {
        v = op_emb[opcode[n] * 32 + (c - 143)];
      } else if (c < 193) {
        v = cfgf[(size_t)n * 18 + (c - 175)];
      }
    }
    smem[r * KP + c] = v;
  }
  __syncthreads();
  const int nloc = threadIdx.x >> 2, jg = threadIdx.x & 3;
  float4 acc[CPT / 4];
  const float4* b4 = (const float4*)(bias + jg * CPT);
#pragma unroll
  for (int j = 0; j < CPT / 4; ++j) acc[j] = b4[j];
  const float* arow = smem + nloc * KP;
  for (int k = 0; k < K; ++k) {
    float f = arow[k];
    const float4* w4 = (const float4*)(wpad + (size_t)k * NC + jg * CPT);
#pragma unroll
    for (int j = 0; j < CPT / 4; ++j) {
      float4 w = w4[j];
      acc[j].x += f * w.x; acc[j].y += f * w.y;
      acc[j].z += f * w.z; acc[j].w += f * w.w;
    }
  }
  int n = base + nloc;
  if (n < N) {
    float4* orow = (float4*)(Out + (size_t)n * NC + jg * CPT);
#pragma unroll
    for (int j = 0; j < CPT / 4; ++j) {
      float4 a = acc[j];
      a.x = fmaxf(a.x, 0.f); a.y = fmaxf(a.y, 0.f);
      a.z = fmaxf(a.z, 0.f); a.w = fmaxf(a.w, 0.f);
      orow[j] = a;
    }
  }
}

// ---------------- generic per-node GEMM ----------------
// Out[n] = epi( A0[n] @ W0 (+ A1[n] @ W1) + bias ), MODE 0 = relu, 1 = row-L2-normalize
// block = 256 threads, 64 nodes/block, 4 threads/node x (NC/4) cols
template <int K0, int K1, int NC, int MODE>
__global__ __launch_bounds__(256) void k_gemm(
    const float* __restrict__ A0, const float* __restrict__ W0,
    const float* __restrict__ A1, const float* __restrict__ W1,
    const float* __restrict__ bias, float* __restrict__ Out, int N) {
  constexpr int CPT = NC / 4;
  constexpr int MK = (K0 > K1 ? K0 : K1);
  __shared__ float smem[64 * (MK + 4)];
  const int base = blockIdx.x * 64;
  const int nloc = threadIdx.x >> 2, jg = threadIdx.x & 3;

  float4 acc[CPT / 4];
  const float4* b4 = (const float4*)(bias + jg * CPT);
#pragma unroll
  for (int j = 0; j < CPT / 4; ++j) acc[j] = b4[j];

  {  // pass 0
    constexpr int K4 = K0 / 4, KP = K0 + 4;
    for (int idx = threadIdx.x; idx < 64 * K4; idx += 256) {
      int r = idx / K4, c4 = idx - r * K4;
      float4 v = make_float4(0.f, 0.f, 0.f, 0.f);
      if (base + r < N) v = ((const float4*)(A0 + (size_t)(base + r) * K0))[c4];
      ((float4*)(smem + r * KP))[c4] = v;
    }
    __syncthreads();
    const float* arow = smem + nloc * KP;
    for (int k = 0; k < K0; ++k) {
      float f = arow[k];
      const float4* w4 = (const float4*)(W0 + (size_t)k * NC + jg * CPT);
#pragma unroll
      for (int j = 0; j < CPT / 4; ++j) {
        float4 w = w4[j];
        acc[j].x += f * w.x; acc[j].y += f * w.y;
        acc[j].z += f * w.z; acc[j].w += f * w.w;
      }
    }
  }
  if constexpr (K1 > 0) {  // pass 1 (reuses LDS)
    __syncthreads();
    constexpr int K4 = K1 / 4, KP = K1 + 4;
    for (int idx = threadIdx.x; idx < 64 * K4; idx += 256) {
      int r = idx / K4, c4 = idx - r * K4;
      float4 v = make_float4(0.f, 0.f, 0.f, 0.f);
      if (base + r < N) v = ((const float4*)(A1 + (size_t)(base + r) * K1))[c4];
      ((float4*)(smem + r * KP))[c4] = v;
    }
    __syncthreads();
    const float* arow = smem + nloc * KP;
    for (int k = 0; k < K1; ++k) {
      float f = arow[k];
      const float4* w4 = (const float4*)(W1 + (size_t)k * NC + jg * CPT);
#pragma unroll
      for (int j = 0; j < CPT / 4; ++j) {
        float4 w = w4[j];
        acc[j].x += f * w.x; acc[j].y += f * w.y;
        acc[j].z += f * w.z; acc[j].w += f * w.w;
      }
    }
  }

  if constexpr (MODE == 1) {  // row L2-normalize across NC (4 lanes per node)
    float ss = 0.f;
#pragma unroll
    for (int j = 0; j < CPT / 4; ++j)
      ss += acc[j].x * acc[j].x + acc[j].y * acc[j].y + acc[j].z * acc[j].z + acc[j].w * acc[j].w;
    ss += __shfl_xor(ss, 1);
    ss += __shfl_xor(ss, 2);
    float scale = 1.f / fmaxf(sqrtf(ss), 1e-12f);
#pragma unroll
    for (int j = 0; j < CPT / 4; ++j) {
      acc[j].x *= scale; acc[j].y *= scale; acc[j].z *= scale; acc[j].w *= scale;
    }
  } else {  // relu
#pragma unroll
    for (int j = 0; j < CPT / 4; ++j) {
      acc[j].x = fmaxf(acc[j].x, 0.f); acc[j].y = fmaxf(acc[j].y, 0.f);
      acc[j].z = fmaxf(acc[j].z, 0.f); acc[j].w = fmaxf(acc[j].w, 0.f);
    }
  }
  if (base + nloc < N) {
    float4* orow = (float4*)(Out + (size_t)(base + nloc) * NC + jg * CPT);
#pragma unroll
    for (int j = 0; j < CPT / 4; ++j) orow[j] = acc[j];
  }
}

// ---------------- CSR mean aggregation: agg[n] = deg_inv[n] * sum_{src in N(n)} xp[src]
template <int NC>
__global__ __launch_bounds__(256) void k_agg(const float* __restrict__ xp,
                                             const int* __restrict__ offs,
                                             const int* __restrict__ esrc,
                                             const float* __restrict__ deginv,
                                             float* __restrict__ agg, int N) {
  int node = blockIdx.x * 4 + (threadIdx.x >> 6);
  int lane = threadIdx.x & 63;
  if (node >= N) return;
  int s0 = offs[node], s1 = offs[node + 1];
  float di = deginv[node];
  if constexpr (NC == 128) {
    float ax = 0.f, ay = 0.f;
    for (int i = s0; i < s1; ++i) {
      int s = esrc[i];
      float2 v = ((const float2*)(xp + (size_t)s * 128))[lane];
      ax += v.x; ay += v.y;
    }
    ((float2*)(agg + (size_t)node * 128))[lane] = make_float2(ax * di, ay * di);
  } else {
    float a = 0.f;
    for (int i = s0; i < s1; ++i) a += xp[(size_t)esrc[i] * 64 + lane];
    agg[(size_t)node * 64 + lane] = a * di;
  }
}

// ---------------- pooling phase 1: per-64-node-chunk partial max/sum/cnt per graph
__global__ __launch_bounds__(256) void k_pool1(const float* __restrict__ x,
                                               const int* __restrict__ batch,
                                               unsigned* __restrict__ gkey,
                                               float* __restrict__ gsum,
                                               int* __restrict__ gcnt, int N) {
  int chunk = blockIdx.x * 4 + (threadIdx.x >> 6);
  int lane = threadIdx.x & 63;
  int n0 = chunk * 64;
  if (n0 >= N) return;
  int n1 = min(n0 + 64, N);
  float rmax = -3.4e38f, rsum = 0.f;
  int rcnt = 0, curb = batch[n0];
  for (int n = n0; n < n1; ++n) {
    int b = batch[n];
    if (b != curb) {
      atomicMax(&gkey[curb * 64 + lane], fkey(rmax));
      atomicAdd(&gsum[curb * 64 + lane], rsum);
      if (lane == 0) atomicAdd(&gcnt[curb], rcnt);
      rmax = -3.4e38f; rsum = 0.f; rcnt = 0; curb = b;
    }
    float v = x[(size_t)n * 64 + lane];
    rmax = fmaxf(rmax, v);
    rsum += v;
    rcnt++;
  }
  atomicMax(&gkey[curb * 64 + lane], fkey(rmax));
  atomicAdd(&gsum[curb * 64 + lane], rsum);
  if (lane == 0) atomicAdd(&gcnt[curb], rcnt);
}

// ---------------- pooling phase 2: g = max + mean; normalize; out = g @ post_w + post_b
__global__ __launch_bounds__(1024) void k_pool2(const unsigned* __restrict__ gkey,
                                                const float* __restrict__ gsum,
                                                const int* __restrict__ gcnt,
                                                const float* __restrict__ post_w,
                                                const float* __restrict__ post_b,
                                                float* __restrict__ out) {
  int b = threadIdx.x >> 6, lane = threadIdx.x & 63;
  float m = funkey(gkey[b * 64 + lane]);
  float s = gsum[b * 64 + lane];
  float c = (float)gcnt[b];
  float g = m + s / fmaxf(c, 1.f);
  float ss = g * g;
#pragma unroll
  for (int off = 1; off < 64; off <<= 1) ss += __shfl_xor(ss, off);
  float gn = g / fmaxf(sqrtf(ss), 1e-30f);
  float contrib = gn * post_w[lane];
#pragma unroll
  for (int off = 1; off < 64; off <<= 1) contrib += __shfl_xor(contrib, off);
  if (lane == 0) out[b] = contrib + post_b[0];
}

extern "C" void kernel_launch(void* const* d_in, const int* in_sizes, int n_in,
                              void* d_out, int out_size, void* d_ws, size_t ws_size,
                              hipStream_t stream) {
  const float* node_feat = (const float*)d_in[0];
  const float* cfgf      = (const float*)d_in[1];
  const int*   opcode    = (const int*)d_in[2];
  const int*   eidx      = (const int*)d_in[3];
  const int*   batch     = (const int*)d_in[4];
  const float* op_emb    = (const float*)d_in[5];
  const float* type_emb  = (const float*)d_in[6];
  const float* lin_w     = (const float*)d_in[7];
  const float* lin_b     = (const float*)d_in[8];
  const float* post_w    = (const float*)d_in[9];
  const float* post_b    = (const float*)d_in[10];
  const float* wp[3] = {(const float*)d_in[11], (const float*)d_in[16], (const float*)d_in[21]};
  const float* bp[3] = {(const float*)d_in[12], (const float*)d_in[17], (const float*)d_in[22]};
  const float* wl[3] = {(const float*)d_in[13], (const float*)d_in[18], (const float*)d_in[23]};
  const float* bl[3] = {(const float*)d_in[14], (const float*)d_in[19], (const float*)d_in[24]};
  const float* wr[3] = {(const float*)d_in[15], (const float*)d_in[20], (const float*)d_in[25]};

  const int N = in_sizes[2];
  const int E = in_sizes[3] / 2;
  const int* e_src = eidx;
  const int* e_dst = eidx + E;

  char* p = (char*)d_ws;
  auto alloc = [&](size_t bytes) -> void* {
    void* r = (void*)p;
    p += (bytes + 255) & ~(size_t)255;
    return r;
  };
  float* R1 = (float*)alloc((size_t)N * 128 * 4);
  float* R2 = (float*)alloc((size_t)N * 128 * 4);
  float* R3 = (float*)alloc((size_t)N * 128 * 4);
  float* wpad = (float*)alloc(196 * 128 * 4);
  int* counts   = (int*)alloc((size_t)N * 4);
  int* offsets  = (int*)alloc((size_t)(N + 1) * 4);
  int* fillpos  = (int*)alloc((size_t)N * 4);
  float* deginv = (float*)alloc((size_t)N * 4);
  int* blockSums = (int*)alloc(1024 * 4);
  int* esrc     = (int*)alloc((size_t)E * 4);
  unsigned* gkey = (unsigned*)alloc(16 * 64 * 4);
  float* gsum    = (float*)alloc(16 * 64 * 4);
  int* gcnt      = (int*)alloc(16 * 4);
  (void)ws_size; (void)n_in; (void)out_size;

  hipMemsetAsync(counts, 0, (size_t)N * 4, stream);
  hipMemsetAsync(gkey, 0, 16 * 64 * 4, stream);
  hipMemsetAsync(gsum, 0, 16 * 64 * 4, stream);
  hipMemsetAsync(gcnt, 0, 16 * 4, stream);

  const int nbE = (E + 255) / 256;
  const int nbN = (N + 255) / 256;
  const int nbG = (N + 63) / 64;
  const int nbA = (N + 3) / 4;
  const int nbP = ((N + 63) / 64 + 3) / 4;

  k_wpad<<<(196 * 128 + 255) / 256, 256, 0, stream>>>(lin_w, wpad);
  k_count<<<nbE, 256, 0, stream>>>(e_dst, counts, E);
  k_scan1<<<nbN, 256, 0, stream>>>(counts, offsets, blockSums, N);
  k_scan2<<<1, 1024, 0, stream>>>(blockSums, nbN);
  k_scan3<<<nbN, 256, 0, stream>>>(counts, offsets, blockSums, fillpos, deginv, N, E);
  k_fill<<<nbE, 256, 0, stream>>>(e_src, e_dst, fillpos, esrc, E);

  // encode: x1 (N x 128) -> R1
  k_encode<<<nbG, 256, 0, stream>>>(node_feat, cfgf, opcode, op_emb, type_emb, wpad, lin_b, R1, N);

  // ---- layer 0 (in 128 -> out 64) ----
  k_gemm<128, 0, 128, 0><<<nbG, 256, 0, stream>>>(R1, wp[0], nullptr, nullptr, bp[0], R2, N);
  k_agg<128><<<nbA, 256, 0, stream>>>(R2, offsets, esrc, deginv, R3, N);
  k_gemm<128, 128, 64, 1><<<nbG, 256, 0, stream>>>(R3, wl[0], R1, wr[0], bl[0], R2, N);
  // ---- layer 1 (x = R2) ----
  k_gemm<64, 0, 64, 0><<<nbG, 256, 0, stream>>>(R2, wp[1], nullptr, nullptr, bp[1], R1, N);
  k_agg<64><<<nbA, 256, 0, stream>>>(R1, offsets, esrc, deginv, R3, N);
  k_gemm<64, 64, 64, 1><<<nbG, 256, 0, stream>>>(R3, wl[1], R2, wr[1], bl[1], R1, N);
  // ---- layer 2 (x = R1) ----
  k_gemm<64, 0, 64, 0><<<nbG, 256, 0, stream>>>(R1, wp[2], nullptr, nullptr, bp[2], R2, N);
  k_agg<64><<<nbA, 256, 0, stream>>>(R2, offsets, esrc, deginv, R3, N);
  k_gemm<64, 64, 64, 1><<<nbG, 256, 0, stream>>>(R3, wl[2], R1, wr[2], bl[2], R2, N);

  // pooling -> out (B=16)
  k_pool1<<<nbP, 256, 0, stream>>>(R2, batch, gkey, gsum, gcnt, N);
  k_pool2<<<1, 1024, 0, stream>>>(gkey, gsum, gcnt, post_w, post_b, (float*)d_out);
}

// Round 2
// 935.427 us; speedup vs baseline: 6.7508x; 6.7508x over previous
//
#include <hip/hip_runtime.h>

typedef _Float16 half8 __attribute__((ext_vector_type(8)));
typedef _Float16 h2 __attribute__((ext_vector_type(2)));
typedef float f32x4 __attribute__((ext_vector_type(4)));

__device__ __forceinline__ unsigned fkey(float f) {
  unsigned u = __float_as_uint(f);
  return (u & 0x80000000u) ? ~u : (u | 0x80000000u);
}
__device__ __forceinline__ float funkey(unsigned k) {
  unsigned u = (k & 0x80000000u) ? (k ^ 0x80000000u) : ~k;
  return __uint_as_float(u);
}

// ---------------- weight convert: fp32 KxNC -> f16 transposed NC x Kpad ----------------
struct WD { const float* src; _Float16* dst; int K, NC, Kpad, base; };
struct WDs { WD d[10]; int total; };

__global__ __launch_bounds__(256) void k_wconv(WDs w) {
  int idx = blockIdx.x * 256 + threadIdx.x;
  if (idx >= w.total) return;
#pragma unroll
  for (int i = 0; i < 10; ++i) {
    int rel = idx - w.d[i].base;
    int sz = w.d[i].NC * w.d[i].Kpad;
    if (rel >= 0 && rel < sz) {
      int n = rel / w.d[i].Kpad;
      int k = rel - n * w.d[i].Kpad;
      w.d[i].dst[rel] = (k < w.d[i].K) ? (_Float16)w.d[i].src[(size_t)k * w.d[i].NC + n]
                                       : (_Float16)0.f;
      return;
    }
  }
}

// ---------------- CSR build ----------------
__global__ __launch_bounds__(256) void k_count(const int* __restrict__ dst,
                                               int* __restrict__ counts, int E) {
  int e = blockIdx.x * 256 + threadIdx.x;
  if (e < E) atomicAdd(&counts[dst[e]], 1);
}

__global__ __launch_bounds__(256) void k_scan1(const int* __restrict__ counts,
                                               int* __restrict__ offsets,
                                               int* __restrict__ blockSums, int N) {
  __shared__ int sm[256];
  int tid = threadIdx.x;
  int gid = blockIdx.x * 256 + tid;
  int v = (gid < N) ? counts[gid] : 0;
  sm[tid] = v;
  __syncthreads();
  for (int off = 1; off < 256; off <<= 1) {
    int t = (tid >= off) ? sm[tid - off] : 0;
    __syncthreads();
    sm[tid] += t;
    __syncthreads();
  }
  if (gid < N) offsets[gid] = sm[tid] - v;
  if (tid == 255) blockSums[blockIdx.x] = sm[255];
}

__global__ __launch_bounds__(1024) void k_scan2(int* __restrict__ blockSums, int NB) {
  __shared__ int sm[1024];
  int tid = threadIdx.x;
  int v = (tid < NB) ? blockSums[tid] : 0;
  sm[tid] = v;
  __syncthreads();
  for (int off = 1; off < 1024; off <<= 1) {
    int t = (tid >= off) ? sm[tid - off] : 0;
    __syncthreads();
    sm[tid] += t;
    __syncthreads();
  }
  if (tid < NB) blockSums[tid] = sm[tid] - v;
}

__global__ __launch_bounds__(256) void k_scan3(const int* __restrict__ counts,
                                               int* __restrict__ offsets,
                                               const int* __restrict__ blockSums,
                                               int* __restrict__ fillpos,
                                               float* __restrict__ deginv, int N, int E) {
  int gid = blockIdx.x * 256 + threadIdx.x;
  if (gid < N) {
    int off = offsets[gid] + blockSums[gid >> 8];
    offsets[gid] = off;
    fillpos[gid] = off;
    deginv[gid] = 1.f / fmaxf((float)counts[gid], 1.f);
  }
  if (gid == 0) offsets[N] = E;
}

__global__ __launch_bounds__(256) void k_fill(const int* __restrict__ src,
                                              const int* __restrict__ dst,
                                              int* __restrict__ fillpos,
                                              int* __restrict__ esrc, int E) {
  int e = blockIdx.x * 256 + threadIdx.x;
  if (e < E) {
    int p = atomicAdd(&fillpos[dst[e]], 1);
    esrc[p] = src[e];
  }
}

// ---------------- feature build: concat -> f16 (N x 224) ----------------
__global__ __launch_bounds__(256) void k_feat(const float* __restrict__ node_feat,
                                              const float* __restrict__ cfgf,
                                              const int* __restrict__ opcode,
                                              const float* __restrict__ op_emb,
                                              const float* __restrict__ type_emb,
                                              _Float16* __restrict__ Out, int N) {
  int idx = blockIdx.x * 256 + threadIdx.x;
  if (idx >= N * 224) return;
  int n = idx / 224;
  int c = idx - n * 224;
  float v = 0.f;
  if (c < 139) {
    v = node_feat[(size_t)n * 140 + c];
  } else if (c < 143) {
    int ty = (int)node_feat[(size_t)n * 140 + 139];
    v = type_emb[ty * 4 + (c - 139)];
  } else if (c < 175) {
    v = op_emb[opcode[n] * 32 + (c - 143)];
  } else if (c < 193) {
    v = cfgf[(size_t)n * 18 + (c - 175)];
  }
  Out[idx] = (_Float16)v;
}

// ---------------- MFMA GEMM ----------------
// Out[r,:] = epi( A0[r]@W0 (+ A1[r]@W1) + bias ), A f16 row-major pitch K, W f16
// transposed (NC x K). MODE 0 = relu, 1 = row L2-normalize.
// 256 thr = 4 waves; 32 rows/wave, 128 rows/block.
template <int K0, int K1, int NC, int MODE>
__global__ __launch_bounds__(256) void k_mm(
    const _Float16* __restrict__ A0, const _Float16* __restrict__ W0,
    const _Float16* __restrict__ A1, const _Float16* __restrict__ W1,
    const float* __restrict__ bias, _Float16* __restrict__ Out, int N) {
  constexpr int NT = NC / 16;
  const int lane = threadIdx.x & 63, wave = threadIdx.x >> 6;
  const int quad = lane >> 4, l15 = lane & 15;
  const int r0 = blockIdx.x * 128 + wave * 32;

  f32x4 acc[2][NT];
#pragma unroll
  for (int rt = 0; rt < 2; ++rt)
#pragma unroll
    for (int t = 0; t < NT; ++t) acc[rt][t] = (f32x4)0.f;

  {
    const _Float16* a0p = A0 + (size_t)(r0 + l15) * K0 + quad * 8;
    const _Float16* a1p = a0p + (size_t)16 * K0;
    const _Float16* wp = W0 + (size_t)l15 * K0 + quad * 8;
#pragma unroll
    for (int k = 0; k < K0; k += 32) {
      half8 a0 = *(const half8*)(a0p + k);
      half8 a1 = *(const half8*)(a1p + k);
#pragma unroll
      for (int t = 0; t < NT; ++t) {
        half8 b = *(const half8*)(wp + (size_t)t * 16 * K0 + k);
        acc[0][t] = __builtin_amdgcn_mfma_f32_16x16x32_f16(a0, b, acc[0][t], 0, 0, 0);
        acc[1][t] = __builtin_amdgcn_mfma_f32_16x16x32_f16(a1, b, acc[1][t], 0, 0, 0);
      }
    }
  }
  if constexpr (K1 > 0) {
    const _Float16* a0p = A1 + (size_t)(r0 + l15) * K1 + quad * 8;
    const _Float16* a1p = a0p + (size_t)16 * K1;
    const _Float16* wp = W1 + (size_t)l15 * K1 + quad * 8;
#pragma unroll
    for (int k = 0; k < K1; k += 32) {
      half8 a0 = *(const half8*)(a0p + k);
      half8 a1 = *(const half8*)(a1p + k);
#pragma unroll
      for (int t = 0; t < NT; ++t) {
        half8 b = *(const half8*)(wp + (size_t)t * 16 * K1 + k);
        acc[0][t] = __builtin_amdgcn_mfma_f32_16x16x32_f16(a0, b, acc[0][t], 0, 0, 0);
        acc[1][t] = __builtin_amdgcn_mfma_f32_16x16x32_f16(a1, b, acc[1][t], 0, 0, 0);
      }
    }
  }

#pragma unroll
  for (int rt = 0; rt < 2; ++rt) {
#pragma unroll
    for (int t = 0; t < NT; ++t) {
      float bv = bias[t * 16 + l15];
      acc[rt][t][0] += bv; acc[rt][t][1] += bv;
      acc[rt][t][2] += bv; acc[rt][t][3] += bv;
    }
    if constexpr (MODE == 1) {
      f32x4 ss = (f32x4)0.f;
#pragma unroll
      for (int t = 0; t < NT; ++t) ss += acc[rt][t] * acc[rt][t];
#pragma unroll
      for (int j = 0; j < 4; ++j) {
        float s = ss[j];
        s += __shfl_xor(s, 1);
        s += __shfl_xor(s, 2);
        s += __shfl_xor(s, 4);
        s += __shfl_xor(s, 8);
        float sc = 1.f / fmaxf(sqrtf(s), 1e-12f);
#pragma unroll
        for (int t = 0; t < NT; ++t) acc[rt][t][j] *= sc;
      }
    } else {
#pragma unroll
      for (int t = 0; t < NT; ++t) {
        acc[rt][t][0] = fmaxf(acc[rt][t][0], 0.f);
        acc[rt][t][1] = fmaxf(acc[rt][t][1], 0.f);
        acc[rt][t][2] = fmaxf(acc[rt][t][2], 0.f);
        acc[rt][t][3] = fmaxf(acc[rt][t][3], 0.f);
      }
    }
#pragma unroll
    for (int j = 0; j < 4; ++j) {
      int r = r0 + rt * 16 + quad * 4 + j;
      if (r < N) {
#pragma unroll
        for (int t = 0; t < NT; ++t)
          Out[(size_t)r * NC + t * 16 + l15] = (_Float16)acc[rt][t][j];
      }
    }
  }
}

// ---------------- CSR mean aggregation (f16 in/out, fp32 accumulate) ----------------
template <int NC>
__global__ __launch_bounds__(256) void k_agg(const _Float16* __restrict__ xp,
                                             const int* __restrict__ offs,
                                             const int* __restrict__ esrc,
                                             const float* __restrict__ deginv,
                                             _Float16* __restrict__ agg, int N) {
  constexpr int LPN = NC / 2;  // lanes per node, dword (2 f16) per lane
  int t = blockIdx.x * 256 + threadIdx.x;
  int node = t / LPN;
  int lane = t - node * LPN;
  if (node >= N) return;
  int s0 = offs[node], s1 = offs[node + 1];
  float ax = 0.f, ay = 0.f;
  for (int i = s0; i < s1; ++i) {
    int s = esrc[i];
    h2 v = ((const h2*)(xp + (size_t)s * NC))[lane];
    ax += (float)v[0];
    ay += (float)v[1];
  }
  float di = deginv[node];
  h2 o;
  o[0] = (_Float16)(ax * di);
  o[1] = (_Float16)(ay * di);
  ((h2*)(agg + (size_t)node * NC))[lane] = o;
}

// ---------------- pooling ----------------
__global__ __launch_bounds__(256) void k_pool1(const _Float16* __restrict__ x,
                                               const int* __restrict__ batch,
                                               unsigned* __restrict__ gkey,
                                               float* __restrict__ gsum,
                                               int* __restrict__ gcnt, int N) {
  int chunk = blockIdx.x * 4 + (threadIdx.x >> 6);
  int lane = threadIdx.x & 63;
  int n0 = chunk * 64;
  if (n0 >= N) return;
  int n1 = min(n0 + 64, N);
  float rmax = -3.4e38f, rsum = 0.f;
  int rcnt = 0, curb = batch[n0];
  for (int n = n0; n < n1; ++n) {
    int b = batch[n];
    if (b != curb) {
      atomicMax(&gkey[curb * 64 + lane], fkey(rmax));
      atomicAdd(&gsum[curb * 64 + lane], rsum);
      if (lane == 0) atomicAdd(&gcnt[curb], rcnt);
      rmax = -3.4e38f; rsum = 0.f; rcnt = 0; curb = b;
    }
    float v = (float)x[(size_t)n * 64 + lane];
    rmax = fmaxf(rmax, v);
    rsum += v;
    rcnt++;
  }
  atomicMax(&gkey[curb * 64 + lane], fkey(rmax));
  atomicAdd(&gsum[curb * 64 + lane], rsum);
  if (lane == 0) atomicAdd(&gcnt[curb], rcnt);
}

__global__ __launch_bounds__(1024) void k_pool2(const unsigned* __restrict__ gkey,
                                                const float* __restrict__ gsum,
                                                const int* __restrict__ gcnt,
                                                const float* __restrict__ post_w,
                                                const float* __restrict__ post_b,
                                                float* __restrict__ out) {
  int b = threadIdx.x >> 6, lane = threadIdx.x & 63;
  float m = funkey(gkey[b * 64 + lane]);
  float s = gsum[b * 64 + lane];
  float c = (float)gcnt[b];
  float g = m + s / fmaxf(c, 1.f);
  float ss = g * g;
#pragma unroll
  for (int off = 1; off < 64; off <<= 1) ss += __shfl_xor(ss, off);
  float gn = g / fmaxf(sqrtf(ss), 1e-30f);
  float contrib = gn * post_w[lane];
#pragma unroll
  for (int off = 1; off < 64; off <<= 1) contrib += __shfl_xor(contrib, off);
  if (lane == 0) out[b] = contrib + post_b[0];
}

extern "C" void kernel_launch(void* const* d_in, const int* in_sizes, int n_in,
                              void* d_out, int out_size, void* d_ws, size_t ws_size,
                              hipStream_t stream) {
  const float* node_feat = (const float*)d_in[0];
  const float* cfgf      = (const float*)d_in[1];
  const int*   opcode    = (const int*)d_in[2];
  const int*   eidx      = (const int*)d_in[3];
  const int*   batch     = (const int*)d_in[4];
  const float* op_emb    = (const float*)d_in[5];
  const float* type_emb  = (const float*)d_in[6];
  const float* lin_w     = (const float*)d_in[7];
  const float* lin_b     = (const float*)d_in[8];
  const float* post_w    = (const float*)d_in[9];
  const float* post_b    = (const float*)d_in[10];
  const float* wp[3] = {(const float*)d_in[11], (const float*)d_in[16], (const float*)d_in[21]};
  const float* bp[3] = {(const float*)d_in[12], (const float*)d_in[17], (const float*)d_in[22]};
  const float* wl[3] = {(const float*)d_in[13], (const float*)d_in[18], (const float*)d_in[23]};
  const float* bl[3] = {(const float*)d_in[14], (const float*)d_in[19], (const float*)d_in[24]};
  const float* wr[3] = {(const float*)d_in[15], (const float*)d_in[20], (const float*)d_in[25]};

  const int N = in_sizes[2];
  const int E = in_sizes[3] / 2;
  const int NPAD = ((N + 127) / 128) * 128;
  const int* e_src = eidx;
  const int* e_dst = eidx + E;

  char* p = (char*)d_ws;
  auto alloc = [&](size_t bytes) -> void* {
    void* r = (void*)p;
    p += (bytes + 255) & ~(size_t)255;
    return r;
  };
  _Float16* F  = (_Float16*)alloc((size_t)NPAD * 224 * 2);  // features
  _Float16* X1 = (_Float16*)alloc((size_t)NPAD * 128 * 2);
  _Float16* R2 = (_Float16*)alloc((size_t)NPAD * 128 * 2);
  _Float16* R3 = (_Float16*)alloc((size_t)NPAD * 128 * 2);
  _Float16* WT = (_Float16*)alloc(86016 * 2);
  int* counts    = (int*)alloc((size_t)N * 4);
  int* offsets   = (int*)alloc((size_t)(N + 1) * 4);
  int* fillpos   = (int*)alloc((size_t)N * 4);
  float* deginv  = (float*)alloc((size_t)N * 4);
  int* blockSums = (int*)alloc(1024 * 4);
  int* esrc      = (int*)alloc((size_t)E * 4);
  unsigned* gkey = (unsigned*)alloc(16 * 64 * 4);
  float* gsum    = (float*)alloc(16 * 64 * 4);
  int* gcnt      = (int*)alloc(16 * 4);
  (void)ws_size; (void)n_in; (void)out_size;

  // transposed f16 weight offsets
  _Float16* WTenc = WT + 0;       // 128 x 224
  _Float16* WTp0  = WT + 28672;   // 128 x 128
  _Float16* WTl0  = WT + 45056;   // 64 x 128
  _Float16* WTr0  = WT + 53248;   // 64 x 128
  _Float16* WTp1  = WT + 61440;   // 64 x 64
  _Float16* WTl1  = WT + 65536;
  _Float16* WTr1  = WT + 69632;
  _Float16* WTp2  = WT + 73728;
  _Float16* WTl2  = WT + 77824;
  _Float16* WTr2  = WT + 81920;   // +4096 = 86016

  WDs wds;
  wds.d[0] = {lin_w, WTenc, 193, 128, 224, 0};
  wds.d[1] = {wp[0], WTp0, 128, 128, 128, 28672};
  wds.d[2] = {wl[0], WTl0, 128, 64, 128, 45056};
  wds.d[3] = {wr[0], WTr0, 128, 64, 128, 53248};
  wds.d[4] = {wp[1], WTp1, 64, 64, 64, 61440};
  wds.d[5] = {wl[1], WTl1, 64, 64, 64, 65536};
  wds.d[6] = {wr[1], WTr1, 64, 64, 64, 69632};
  wds.d[7] = {wp[2], WTp2, 64, 64, 64, 73728};
  wds.d[8] = {wl[2], WTl2, 64, 64, 64, 77824};
  wds.d[9] = {wr[2], WTr2, 64, 64, 64, 81920};
  wds.total = 86016;

  hipMemsetAsync(counts, 0, (size_t)N * 4, stream);
  hipMemsetAsync(gkey, 0, 16 * 64 * 4, stream);
  hipMemsetAsync(gsum, 0, 16 * 64 * 4, stream);
  hipMemsetAsync(gcnt, 0, 16 * 4, stream);

  const int nbE = (E + 255) / 256;
  const int nbN = (N + 255) / 256;
  const int nbMM = NPAD / 128;
  const int nbA128 = ((size_t)N * 64 + 255) / 256;
  const int nbA64  = ((size_t)N * 32 + 255) / 256;
  const int nbP = ((N + 63) / 64 + 3) / 4;

  k_wconv<<<(86016 + 255) / 256, 256, 0, stream>>>(wds);
  k_count<<<nbE, 256, 0, stream>>>(e_dst, counts, E);
  k_scan1<<<nbN, 256, 0, stream>>>(counts, offsets, blockSums, N);
  k_scan2<<<1, 1024, 0, stream>>>(blockSums, nbN);
  k_scan3<<<nbN, 256, 0, stream>>>(counts, offsets, blockSums, fillpos, deginv, N, E);
  k_fill<<<nbE, 256, 0, stream>>>(e_src, e_dst, fillpos, esrc, E);

  k_feat<<<((size_t)N * 224 + 255) / 256, 256, 0, stream>>>(node_feat, cfgf, opcode, op_emb,
                                                            type_emb, F, N);
  // encode: relu(F @ Wenc + lin_b) -> X1 (N x 128)
  k_mm<224, 0, 128, 0><<<nbMM, 256, 0, stream>>>(F, WTenc, nullptr, nullptr, lin_b, X1, N);

  // ---- layer 0 ----
  k_mm<128, 0, 128, 0><<<nbMM, 256, 0, stream>>>(X1, WTp0, nullptr, nullptr, bp[0], R2, N);
  k_agg<128><<<nbA128, 256, 0, stream>>>(R2, offsets, esrc, deginv, R3, N);
  k_mm<128, 128, 64, 1><<<nbMM, 256, 0, stream>>>(R3, WTl0, X1, WTr0, bl[0], R2, N);
  // ---- layer 1 ----
  k_mm<64, 0, 64, 0><<<nbMM, 256, 0, stream>>>(R2, WTp1, nullptr, nullptr, bp[1], R3, N);
  k_agg<64><<<nbA64, 256, 0, stream>>>(R3, offsets, esrc, deginv, X1, N);
  k_mm<64, 64, 64, 1><<<nbMM, 256, 0, stream>>>(X1, WTl1, R2, WTr1, bl[1], R3, N);
  // ---- layer 2 ----
  k_mm<64, 0, 64, 0><<<nbMM, 256, 0, stream>>>(R3, WTp2, nullptr, nullptr, bp[2], X1, N);
  k_agg<64><<<nbA64, 256, 0, stream>>>(X1, offsets, esrc, deginv, R2, N);
  k_mm<64, 64, 64, 1><<<nbMM, 256, 0, stream>>>(R2, WTl2, R3, WTr2, bl[2], X1, N);

  // pooling -> out (B=16)
  k_pool1<<<nbP, 256, 0, stream>>>(X1, batch, gkey, gsum, gcnt, N);
  k_pool2<<<1, 1024, 0, stream>>>(gkey, gsum, gcnt, post_w, post_b, (float*)d_out);
}

// Round 3
// 870.771 us; speedup vs baseline: 7.2521x; 1.0743x over previous
//
#include <hip/hip_runtime.h>

typedef _Float16 half8 __attribute__((ext_vector_type(8)));
typedef _Float16 h4 __attribute__((ext_vector_type(4)));
typedef _Float16 h2 __attribute__((ext_vector_type(2)));
typedef float f32x4 __attribute__((ext_vector_type(4)));

__device__ __forceinline__ unsigned fkey(float f) {
  unsigned u = __float_as_uint(f);
  return (u & 0x80000000u) ? ~u : (u | 0x80000000u);
}
__device__ __forceinline__ float funkey(unsigned k) {
  unsigned u = (k & 0x80000000u) ? (k ^ 0x80000000u) : ~k;
  return __uint_as_float(u);
}

// ---------------- weight convert: fp32 KxNC -> f16 transposed NC x Kpad ----------------
struct WD { const float* src; _Float16* dst; int K, NC, Kpad, base; };
struct WDs { WD d[10]; int total; };

__global__ __launch_bounds__(256) void k_wconv(WDs w) {
  int idx = blockIdx.x * 256 + threadIdx.x;
  if (idx >= w.total) return;
#pragma unroll
  for (int i = 0; i < 10; ++i) {
    int rel = idx - w.d[i].base;
    int sz = w.d[i].NC * w.d[i].Kpad;
    if (rel >= 0 && rel < sz) {
      int n = rel / w.d[i].Kpad;
      int k = rel - n * w.d[i].Kpad;
      w.d[i].dst[rel] = (k < w.d[i].K) ? (_Float16)w.d[i].src[(size_t)k * w.d[i].NC + n]
                                       : (_Float16)0.f;
      return;
    }
  }
}

// ---------------- CSR build ----------------
__global__ __launch_bounds__(256) void k_count(const int* __restrict__ dst,
                                               int* __restrict__ counts, int E) {
  int e = blockIdx.x * 256 + threadIdx.x;
  if (e < E) atomicAdd(&counts[dst[e]], 1);
}

__global__ __launch_bounds__(256) void k_scan1(const int* __restrict__ counts,
                                               int* __restrict__ offsets,
                                               int* __restrict__ blockSums, int N) {
  __shared__ int sm[256];
  int tid = threadIdx.x;
  int gid = blockIdx.x * 256 + tid;
  int v = (gid < N) ? counts[gid] : 0;
  sm[tid] = v;
  __syncthreads();
  for (int off = 1; off < 256; off <<= 1) {
    int t = (tid >= off) ? sm[tid - off] : 0;
    __syncthreads();
    sm[tid] += t;
    __syncthreads();
  }
  if (gid < N) offsets[gid] = sm[tid] - v;
  if (tid == 255) blockSums[blockIdx.x] = sm[255];
}

__global__ __launch_bounds__(1024) void k_scan2(int* __restrict__ blockSums, int NB) {
  __shared__ int sm[1024];
  int tid = threadIdx.x;
  int v = (tid < NB) ? blockSums[tid] : 0;
  sm[tid] = v;
  __syncthreads();
  for (int off = 1; off < 1024; off <<= 1) {
    int t = (tid >= off) ? sm[tid - off] : 0;
    __syncthreads();
    sm[tid] += t;
    __syncthreads();
  }
  if (tid < NB) blockSums[tid] = sm[tid] - v;
}

__global__ __launch_bounds__(256) void k_scan3(const int* __restrict__ counts,
                                               int* __restrict__ offsets,
                                               const int* __restrict__ blockSums,
                                               int* __restrict__ fillpos,
                                               float* __restrict__ deginv, int N, int E) {
  int gid = blockIdx.x * 256 + threadIdx.x;
  if (gid < N) {
    int off = offsets[gid] + blockSums[gid >> 8];
    offsets[gid] = off;
    fillpos[gid] = off;
    deginv[gid] = 1.f / fmaxf((float)counts[gid], 1.f);
  }
  if (gid == 0) offsets[N] = E;
}

__global__ __launch_bounds__(256) void k_fill(const int* __restrict__ src,
                                              const int* __restrict__ dst,
                                              int* __restrict__ fillpos,
                                              int* __restrict__ esrc, int E) {
  int e = blockIdx.x * 256 + threadIdx.x;
  if (e < E) {
    int p = atomicAdd(&fillpos[dst[e]], 1);
    esrc[p] = src[e];
  }
}

// ---------------- feature build: concat -> f16 (N x 224), 4 cols/thread ----------------
__global__ __launch_bounds__(256) void k_feat(const float* __restrict__ node_feat,
                                              const float* __restrict__ cfgf,
                                              const int* __restrict__ opcode,
                                              const float* __restrict__ op_emb,
                                              const float* __restrict__ type_emb,
                                              _Float16* __restrict__ Out, int N) {
  int idx = blockIdx.x * 256 + threadIdx.x;
  if (idx >= N * 56) return;
  int n = idx / 56;
  int c4 = (idx - n * 56) * 4;
  float4 v = make_float4(0.f, 0.f, 0.f, 0.f);
  if (c4 < 136) {
    v = *(const float4*)(node_feat + (size_t)n * 140 + c4);
  } else if (c4 == 136) {
    const float* f = node_feat + (size_t)n * 140;
    int ty = (int)f[139];
    v.x = f[136]; v.y = f[137]; v.z = f[138];
    v.w = type_emb[ty * 4 + 0];
  } else if (c4 == 140) {
    int ty = (int)node_feat[(size_t)n * 140 + 139];
    v.x = type_emb[ty * 4 + 1];
    v.y = type_emb[ty * 4 + 2];
    v.z = type_emb[ty * 4 + 3];
    v.w = op_emb[opcode[n] * 32 + 0];
  } else if (c4 < 172) {  // op_emb cols 1..28
    const float* o = op_emb + opcode[n] * 32 + (c4 - 143);
    v.x = o[0]; v.y = o[1]; v.z = o[2]; v.w = o[3];
  } else if (c4 == 172) {
    const float* o = op_emb + opcode[n] * 32;
    v.x = o[29]; v.y = o[30]; v.z = o[31];
    v.w = cfgf[(size_t)n * 18 + 0];
  } else if (c4 < 192) {  // cfg cols 1..16
    const float* c = cfgf + (size_t)n * 18 + (c4 - 175);
    v.x = c[0]; v.y = c[1]; v.z = c[2]; v.w = c[3];
  } else if (c4 == 192) {
    v.x = cfgf[(size_t)n * 18 + 17];
  }
  h4 o;
  o[0] = (_Float16)v.x; o[1] = (_Float16)v.y;
  o[2] = (_Float16)v.z; o[3] = (_Float16)v.w;
  *(h4*)(Out + (size_t)n * 224 + c4) = o;
}

// ---------------- MFMA GEMM, B staged in LDS ----------------
// Out[r,:] = epi( A0[r]@W0 (+ A1[r]@W1) + bias ), A f16 row-major pitch K, W f16
// transposed (NC x K). MODE 0 = relu, 1 = row L2-normalize.
// 256 thr = 4 waves; 64 rows/wave (4 row-tiles), 256 rows/block.
template <int K0, int K1, int NC, int MODE>
__global__ __launch_bounds__(256) void k_mm(
    const _Float16* __restrict__ A0, const _Float16* __restrict__ W0,
    const _Float16* __restrict__ A1, const _Float16* __restrict__ W1,
    const float* __restrict__ bias, _Float16* __restrict__ Out, int N) {
  constexpr int NT = NC / 16;  // col tiles
  constexpr int RT = 4;        // row tiles per wave
  constexpr int KP0 = K0 + 8;  // padded LDS pitch (f16): 4*odd dwords -> conflict-free
  constexpr int KP1 = K1 + 8;
  __shared__ _Float16 sB0[NC * KP0];
  __shared__ _Float16 sB1[(K1 > 0) ? (NC * KP1) : 8];

  for (int idx = threadIdx.x; idx < NC * (K0 / 8); idx += 256) {
    int nn = idx / (K0 / 8), k8 = idx - nn * (K0 / 8);
    *(half8*)(sB0 + nn * KP0 + k8 * 8) = *(const half8*)(W0 + (size_t)nn * K0 + k8 * 8);
  }
  if constexpr (K1 > 0) {
    for (int idx = threadIdx.x; idx < NC * (K1 / 8); idx += 256) {
      int nn = idx / (K1 / 8), k8 = idx - nn * (K1 / 8);
      *(half8*)(sB1 + nn * KP1 + k8 * 8) = *(const half8*)(W1 + (size_t)nn * K1 + k8 * 8);
    }
  }
  __syncthreads();

  const int lane = threadIdx.x & 63, wave = threadIdx.x >> 6;
  const int quad = lane >> 4, l15 = lane & 15;
  const int r0 = blockIdx.x * 256 + wave * 64;

  f32x4 acc[RT][NT];
#pragma unroll
  for (int rt = 0; rt < RT; ++rt)
#pragma unroll
    for (int t = 0; t < NT; ++t) acc[rt][t] = (f32x4)0.f;

  {
    const _Float16* ap = A0 + (size_t)(r0 + l15) * K0 + quad * 8;
#pragma unroll
    for (int k = 0; k < K0; k += 32) {
      half8 a[RT];
#pragma unroll
      for (int rt = 0; rt < RT; ++rt) a[rt] = *(const half8*)(ap + (size_t)rt * 16 * K0 + k);
#pragma unroll
      for (int t = 0; t < NT; ++t) {
        half8 b = *(const half8*)(sB0 + (t * 16 + l15) * KP0 + quad * 8 + k);
#pragma unroll
        for (int rt = 0; rt < RT; ++rt)
          acc[rt][t] = __builtin_amdgcn_mfma_f32_16x16x32_f16(a[rt], b, acc[rt][t], 0, 0, 0);
      }
    }
  }
  if constexpr (K1 > 0) {
    const _Float16* ap = A1 + (size_t)(r0 + l15) * K1 + quad * 8;
#pragma unroll
    for (int k = 0; k < K1; k += 32) {
      half8 a[RT];
#pragma unroll
      for (int rt = 0; rt < RT; ++rt) a[rt] = *(const half8*)(ap + (size_t)rt * 16 * K1 + k);
#pragma unroll
      for (int t = 0; t < NT; ++t) {
        half8 b = *(const half8*)(sB1 + (t * 16 + l15) * KP1 + quad * 8 + k);
#pragma unroll
        for (int rt = 0; rt < RT; ++rt)
          acc[rt][t] = __builtin_amdgcn_mfma_f32_16x16x32_f16(a[rt], b, acc[rt][t], 0, 0, 0);
      }
    }
  }

#pragma unroll
  for (int rt = 0; rt < RT; ++rt) {
#pragma unroll
    for (int t = 0; t < NT; ++t) {
      float bv = bias[t * 16 + l15];
      acc[rt][t][0] += bv; acc[rt][t][1] += bv;
      acc[rt][t][2] += bv; acc[rt][t][3] += bv;
    }
    if constexpr (MODE == 1) {
      f32x4 ss = (f32x4)0.f;
#pragma unroll
      for (int t = 0; t < NT; ++t) ss += acc[rt][t] * acc[rt][t];
#pragma unroll
      for (int j = 0; j < 4; ++j) {
        float s = ss[j];
        s += __shfl_xor(s, 1);
        s += __shfl_xor(s, 2);
        s += __shfl_xor(s, 4);
        s += __shfl_xor(s, 8);
        float sc = 1.f / fmaxf(sqrtf(s), 1e-12f);
#pragma unroll
        for (int t = 0; t < NT; ++t) acc[rt][t][j] *= sc;
      }
    } else {
#pragma unroll
      for (int t = 0; t < NT; ++t) {
        acc[rt][t][0] = fmaxf(acc[rt][t][0], 0.f);
        acc[rt][t][1] = fmaxf(acc[rt][t][1], 0.f);
        acc[rt][t][2] = fmaxf(acc[rt][t][2], 0.f);
        acc[rt][t][3] = fmaxf(acc[rt][t][3], 0.f);
      }
    }
#pragma unroll
    for (int j = 0; j < 4; ++j) {
      int r = r0 + rt * 16 + quad * 4 + j;
      if (r < N) {
#pragma unroll
        for (int t = 0; t < NT; ++t)
          Out[(size_t)r * NC + t * 16 + l15] = (_Float16)acc[rt][t][j];
      }
    }
  }
}

// ---------------- CSR mean aggregation (f16 in/out, fp32 accumulate) ----------------
template <int NC>
__global__ __launch_bounds__(256) void k_agg(const _Float16* __restrict__ xp,
                                             const int* __restrict__ offs,
                                             const int* __restrict__ esrc,
                                             const float* __restrict__ deginv,
                                             _Float16* __restrict__ agg, int N) {
  constexpr int LPN = NC / 2;
  int t = blockIdx.x * 256 + threadIdx.x;
  int node = t / LPN;
  int lane = t - node * LPN;
  if (node >= N) return;
  int s0 = offs[node], s1 = offs[node + 1];
  float ax = 0.f, ay = 0.f;
  for (int i = s0; i < s1; ++i) {
    int s = esrc[i];
    h2 v = ((const h2*)(xp + (size_t)s * NC))[lane];
    ax += (float)v[0];
    ay += (float)v[1];
  }
  float di = deginv[node];
  h2 o;
  o[0] = (_Float16)(ax * di);
  o[1] = (_Float16)(ay * di);
  ((h2*)(agg + (size_t)node * NC))[lane] = o;
}

// ---------------- pooling ----------------
__global__ __launch_bounds__(256) void k_pool1(const _Float16* __restrict__ x,
                                               const int* __restrict__ batch,
                                               unsigned* __restrict__ gkey,
                                               float* __restrict__ gsum,
                                               int* __restrict__ gcnt, int N) {
  int chunk = blockIdx.x * 4 + (threadIdx.x >> 6);
  int lane = threadIdx.x & 63;
  int n0 = chunk * 64;
  if (n0 >= N) return;
  int n1 = min(n0 + 64, N);
  float rmax = -3.4e38f, rsum = 0.f;
  int rcnt = 0, curb = batch[n0];
  for (int n = n0; n < n1; ++n) {
    int b = batch[n];
    if (b != curb) {
      atomicMax(&gkey[curb * 64 + lane], fkey(rmax));
      atomicAdd(&gsum[curb * 64 + lane], rsum);
      if (lane == 0) atomicAdd(&gcnt[curb], rcnt);
      rmax = -3.4e38f; rsum = 0.f; rcnt = 0; curb = b;
    }
    float v = (float)x[(size_t)n * 64 + lane];
    rmax = fmaxf(rmax, v);
    rsum += v;
    rcnt++;
  }
  atomicMax(&gkey[curb * 64 + lane], fkey(rmax));
  atomicAdd(&gsum[curb * 64 + lane], rsum);
  if (lane == 0) atomicAdd(&gcnt[curb], rcnt);
}

__global__ __launch_bounds__(1024) void k_pool2(const unsigned* __restrict__ gkey,
                                                const float* __restrict__ gsum,
                                                const int* __restrict__ gcnt,
                                                const float* __restrict__ post_w,
                                                const float* __restrict__ post_b,
                                                float* __restrict__ out) {
  int b = threadIdx.x >> 6, lane = threadIdx.x & 63;
  float m = funkey(gkey[b * 64 + lane]);
  float s = gsum[b * 64 + lane];
  float c = (float)gcnt[b];
  float g = m + s / fmaxf(c, 1.f);
  float ss = g * g;
#pragma unroll
  for (int off = 1; off < 64; off <<= 1) ss += __shfl_xor(ss, off);
  float gn = g / fmaxf(sqrtf(ss), 1e-30f);
  float contrib = gn * post_w[lane];
#pragma unroll
  for (int off = 1; off < 64; off <<= 1) contrib += __shfl_xor(contrib, off);
  if (lane == 0) out[b] = contrib + post_b[0];
}

extern "C" void kernel_launch(void* const* d_in, const int* in_sizes, int n_in,
                              void* d_out, int out_size, void* d_ws, size_t ws_size,
                              hipStream_t stream) {
  const float* node_feat = (const float*)d_in[0];
  const float* cfgf      = (const float*)d_in[1];
  const int*   opcode    = (const int*)d_in[2];
  const int*   eidx      = (const int*)d_in[3];
  const int*   batch     = (const int*)d_in[4];
  const float* op_emb    = (const float*)d_in[5];
  const float* type_emb  = (const float*)d_in[6];
  const float* lin_w     = (const float*)d_in[7];
  const float* lin_b     = (const float*)d_in[8];
  const float* post_w    = (const float*)d_in[9];
  const float* post_b    = (const float*)d_in[10];
  const float* wp[3] = {(const float*)d_in[11], (const float*)d_in[16], (const float*)d_in[21]};
  const float* bp[3] = {(const float*)d_in[12], (const float*)d_in[17], (const float*)d_in[22]};
  const float* wl[3] = {(const float*)d_in[13], (const float*)d_in[18], (const float*)d_in[23]};
  const float* bl[3] = {(const float*)d_in[14], (const float*)d_in[19], (const float*)d_in[24]};
  const float* wr[3] = {(const float*)d_in[15], (const float*)d_in[20], (const float*)d_in[25]};

  const int N = in_sizes[2];
  const int E = in_sizes[3] / 2;
  const int NPAD = ((N + 255) / 256) * 256;
  const int* e_src = eidx;
  const int* e_dst = eidx + E;

  char* p = (char*)d_ws;
  auto alloc = [&](size_t bytes) -> void* {
    void* r = (void*)p;
    p += (bytes + 255) & ~(size_t)255;
    return r;
  };
  _Float16* F  = (_Float16*)alloc((size_t)NPAD * 224 * 2);
  _Float16* X1 = (_Float16*)alloc((size_t)NPAD * 128 * 2);
  _Float16* R2 = (_Float16*)alloc((size_t)NPAD * 128 * 2);
  _Float16* R3 = (_Float16*)alloc((size_t)NPAD * 128 * 2);
  _Float16* WT = (_Float16*)alloc(86016 * 2);
  int* counts    = (int*)alloc((size_t)N * 4);
  int* offsets   = (int*)alloc((size_t)(N + 1) * 4);
  int* fillpos   = (int*)alloc((size_t)N * 4);
  float* deginv  = (float*)alloc((size_t)N * 4);
  int* blockSums = (int*)alloc(1024 * 4);
  int* esrc      = (int*)alloc((size_t)E * 4);
  unsigned* gkey = (unsigned*)alloc(16 * 64 * 4);
  float* gsum    = (float*)alloc(16 * 64 * 4);
  int* gcnt      = (int*)alloc(16 * 4);
  (void)ws_size; (void)n_in; (void)out_size;

  _Float16* WTenc = WT + 0;       // 128 x 224
  _Float16* WTp0  = WT + 28672;   // 128 x 128
  _Float16* WTl0  = WT + 45056;   // 64 x 128
  _Float16* WTr0  = WT + 53248;   // 64 x 128
  _Float16* WTp1  = WT + 61440;   // 64 x 64
  _Float16* WTl1  = WT + 65536;
  _Float16* WTr1  = WT + 69632;
  _Float16* WTp2  = WT + 73728;
  _Float16* WTl2  = WT + 77824;
  _Float16* WTr2  = WT + 81920;

  WDs wds;
  wds.d[0] = {lin_w, WTenc, 193, 128, 224, 0};
  wds.d[1] = {wp[0], WTp0, 128, 128, 128, 28672};
  wds.d[2] = {wl[0], WTl0, 128, 64, 128, 45056};
  wds.d[3] = {wr[0], WTr0, 128, 64, 128, 53248};
  wds.d[4] = {wp[1], WTp1, 64, 64, 64, 61440};
  wds.d[5] = {wl[1], WTl1, 64, 64, 64, 65536};
  wds.d[6] = {wr[1], WTr1, 64, 64, 64, 69632};
  wds.d[7] = {wp[2], WTp2, 64, 64, 64, 73728};
  wds.d[8] = {wl[2], WTl2, 64, 64, 64, 77824};
  wds.d[9] = {wr[2], WTr2, 64, 64, 64, 81920};
  wds.total = 86016;

  hipMemsetAsync(counts, 0, (size_t)N * 4, stream);
  hipMemsetAsync(gkey, 0, 16 * 64 * 4, stream);
  hipMemsetAsync(gsum, 0, 16 * 64 * 4, stream);
  hipMemsetAsync(gcnt, 0, 16 * 4, stream);

  const int nbE = (E + 255) / 256;
  const int nbN = (N + 255) / 256;
  const int nbMM = NPAD / 256;
  const int nbA128 = ((size_t)N * 64 + 255) / 256;
  const int nbA64  = ((size_t)N * 32 + 255) / 256;
  const int nbP = ((N + 63) / 64 + 3) / 4;

  k_wconv<<<(86016 + 255) / 256, 256, 0, stream>>>(wds);
  k_count<<<nbE, 256, 0, stream>>>(e_dst, counts, E);
  k_scan1<<<nbN, 256, 0, stream>>>(counts, offsets, blockSums, N);
  k_scan2<<<1, 1024, 0, stream>>>(blockSums, nbN);
  k_scan3<<<nbN, 256, 0, stream>>>(counts, offsets, blockSums, fillpos, deginv, N, E);
  k_fill<<<nbE, 256, 0, stream>>>(e_src, e_dst, fillpos, esrc, E);

  k_feat<<<((size_t)N * 56 + 255) / 256, 256, 0, stream>>>(node_feat, cfgf, opcode, op_emb,
                                                           type_emb, F, N);
  // encode: relu(F @ Wenc + lin_b) -> X1 (N x 128)
  k_mm<224, 0, 128, 0><<<nbMM, 256, 0, stream>>>(F, WTenc, nullptr, nullptr, lin_b, X1, N);

  // ---- layer 0 ----
  k_mm<128, 0, 128, 0><<<nbMM, 256, 0, stream>>>(X1, WTp0, nullptr, nullptr, bp[0], R2, N);
  k_agg<128><<<nbA128, 256, 0, stream>>>(R2, offsets, esrc, deginv, R3, N);
  k_mm<128, 128, 64, 1><<<nbMM, 256, 0, stream>>>(R3, WTl0, X1, WTr0, bl[0], R2, N);
  // ---- layer 1 ----
  k_mm<64, 0, 64, 0><<<nbMM, 256, 0, stream>>>(R2, WTp1, nullptr, nullptr, bp[1], R3, N);
  k_agg<64><<<nbA64, 256, 0, stream>>>(R3, offsets, esrc, deginv, X1, N);
  k_mm<64, 64, 64, 1><<<nbMM, 256, 0, stream>>>(X1, WTl1, R2, WTr1, bl[1], R3, N);
  // ---- layer 2 ----
  k_mm<64, 0, 64, 0><<<nbMM, 256, 0, stream>>>(R3, WTp2, nullptr, nullptr, bp[2], X1, N);
  k_agg<64><<<nbA64, 256, 0, stream>>>(X1, offsets, esrc, deginv, R2, N);
  k_mm<64, 64, 64, 1><<<nbMM, 256, 0, stream>>>(R2, WTl2, R3, WTr2, bl[2], X1, N);

  // pooling -> out (B=16)
  k_pool1<<<nbP, 256, 0, stream>>>(X1, batch, gkey, gsum, gcnt, N);
  k_pool2<<<1, 1024, 0, stream>>>(gkey, gsum, gcnt, post_w, post_b, (float*)d_out);
}

// Round 4
// 705.855 us; speedup vs baseline: 8.9464x; 1.2336x over previous
//
#include <hip/hip_runtime.h>

typedef _Float16 half8 __attribute__((ext_vector_type(8)));
typedef _Float16 h4 __attribute__((ext_vector_type(4)));
typedef _Float16 h2 __attribute__((ext_vector_type(2)));
typedef float f32x4 __attribute__((ext_vector_type(4)));

__device__ __forceinline__ unsigned fkey(float f) {
  unsigned u = __float_as_uint(f);
  return (u & 0x80000000u) ? ~u : (u | 0x80000000u);
}
__device__ __forceinline__ float funkey(unsigned k) {
  unsigned u = (k & 0x80000000u) ? (k ^ 0x80000000u) : ~k;
  return __uint_as_float(u);
}

// ---------------- weight convert: fp32 KxNC -> f16 transposed NC x Kpad ----------------
struct WD { const float* src; _Float16* dst; int K, NC, Kpad, base; };
struct WDs { WD d[10]; int total; };

__global__ __launch_bounds__(256) void k_wconv(WDs w) {
  int idx = blockIdx.x * 256 + threadIdx.x;
  if (idx >= w.total) return;
#pragma unroll
  for (int i = 0; i < 10; ++i) {
    int rel = idx - w.d[i].base;
    int sz = w.d[i].NC * w.d[i].Kpad;
    if (rel >= 0 && rel < sz) {
      int n = rel / w.d[i].Kpad;
      int k = rel - n * w.d[i].Kpad;
      w.d[i].dst[rel] = (k < w.d[i].K) ? (_Float16)w.d[i].src[(size_t)k * w.d[i].NC + n]
                                       : (_Float16)0.f;
      return;
    }
  }
}

// ---------------- CSR build ----------------
__global__ __launch_bounds__(256) void k_count(const int* __restrict__ dst,
                                               int* __restrict__ counts, int E) {
  int e = blockIdx.x * 256 + threadIdx.x;
  if (e < E) atomicAdd(&counts[dst[e]], 1);
}

__global__ __launch_bounds__(256) void k_scan1(const int* __restrict__ counts,
                                               int* __restrict__ offsets,
                                               int* __restrict__ blockSums, int N) {
  __shared__ int sm[256];
  int tid = threadIdx.x;
  int gid = blockIdx.x * 256 + tid;
  int v = (gid < N) ? counts[gid] : 0;
  sm[tid] = v;
  __syncthreads();
  for (int off = 1; off < 256; off <<= 1) {
    int t = (tid >= off) ? sm[tid - off] : 0;
    __syncthreads();
    sm[tid] += t;
    __syncthreads();
  }
  if (gid < N) offsets[gid] = sm[tid] - v;
  if (tid == 255) blockSums[blockIdx.x] = sm[255];
}

__global__ __launch_bounds__(1024) void k_scan2(int* __restrict__ blockSums, int NB) {
  __shared__ int sm[1024];
  int tid = threadIdx.x;
  int v = (tid < NB) ? blockSums[tid] : 0;
  sm[tid] = v;
  __syncthreads();
  for (int off = 1; off < 1024; off <<= 1) {
    int t = (tid >= off) ? sm[tid - off] : 0;
    __syncthreads();
    sm[tid] += t;
    __syncthreads();
  }
  if (tid < NB) blockSums[tid] = sm[tid] - v;
}

__global__ __launch_bounds__(256) void k_scan3(const int* __restrict__ counts,
                                               int* __restrict__ offsets,
                                               const int* __restrict__ blockSums,
                                               int* __restrict__ fillpos,
                                               float* __restrict__ deginv, int N, int E) {
  int gid = blockIdx.x * 256 + threadIdx.x;
  if (gid < N) {
    int off = offsets[gid] + blockSums[gid >> 8];
    offsets[gid] = off;
    fillpos[gid] = off;
    deginv[gid] = 1.f / fmaxf((float)counts[gid], 1.f);
  }
  if (gid == 0) offsets[N] = E;
}

__global__ __launch_bounds__(256) void k_fill(const int* __restrict__ src,
                                              const int* __restrict__ dst,
                                              int* __restrict__ fillpos,
                                              int* __restrict__ esrc, int E) {
  int e = blockIdx.x * 256 + threadIdx.x;
  if (e < E) {
    int p = atomicAdd(&fillpos[dst[e]], 1);
    esrc[p] = src[e];
  }
}

// ---------------- feature build: LDS-staged concat -> f16 (N x 224) ----------------
// block = 256 threads, 64 nodes. Stage node_feat (pitch 140, verbatim span copy) +
// cfg + opcode in LDS with dense coalesced loads; assemble output from LDS only.
__global__ __launch_bounds__(256) void k_feat(const float* __restrict__ node_feat,
                                              const float* __restrict__ cfgf,
                                              const int* __restrict__ opcode,
                                              const float* __restrict__ op_emb,
                                              const float* __restrict__ type_emb,
                                              _Float16* __restrict__ Out, int N) {
  __shared__ float sF[64 * 140];
  __shared__ float sC[64 * 18];
  __shared__ int sOp[64];
  const int base = blockIdx.x * 64;
  const int nrem = min(64, N - base);

  {  // node_feat span: nrem*140 floats, 140%4==0 -> exact float4 count, 16B-aligned
    const float4* g = (const float4*)(node_feat + (size_t)base * 140);
    const int tot4 = (nrem * 140) >> 2;
    for (int i = threadIdx.x; i < tot4; i += 256) *(float4*)(sF + i * 4) = g[i];
  }
  {  // cfg span: scalar dwords (avoid tail overread)
    const float* g = cfgf + (size_t)base * 18;
    const int tot = nrem * 18;
    for (int i = threadIdx.x; i < tot; i += 256) sC[i] = g[i];
  }
  if (threadIdx.x < 64)
    sOp[threadIdx.x] = (base + threadIdx.x < N) ? opcode[base + threadIdx.x] : 0;
  __syncthreads();

  // 64 nodes x 28 chunks of 8 cols = 1792 chunks; 7 per thread
#pragma unroll
  for (int it = 0; it < 7; ++it) {
    int chunk = it * 256 + threadIdx.x;
    int r = chunk / 28;
    int c0 = (chunk - r * 28) * 8;
    if (r >= nrem) continue;
    const float* fr = sF + r * 140;
    float v[8];
    if (c0 <= 128) {
#pragma unroll
      for (int j = 0; j < 8; ++j) v[j] = fr[c0 + j];
    } else if (c0 == 136) {  // cols 136..143: feat 136-138 | type 0-3 | op 0
      v[0] = fr[136]; v[1] = fr[137]; v[2] = fr[138];
      int ty = min(max((int)fr[139], 0), 7);
      const float* te = type_emb + ty * 4;
      v[3] = te[0]; v[4] = te[1]; v[5] = te[2]; v[6] = te[3];
      v[7] = op_emb[sOp[r] * 32 + 0];
    } else if (c0 < 168) {  // op cols 1..24
      const float* o = op_emb + sOp[r] * 32 + (c0 - 143);
#pragma unroll
      for (int j = 0; j < 8; ++j) v[j] = o[j];
    } else if (c0 == 168) {  // op 25..31 | cfg 0
      const float* o = op_emb + sOp[r] * 32;
#pragma unroll
      for (int j = 0; j < 7; ++j) v[j] = o[25 + j];
      v[7] = sC[r * 18 + 0];
    } else if (c0 < 192) {  // cfg 1..16
      const float* c = sC + r * 18 + (c0 - 175);
#pragma unroll
      for (int j = 0; j < 8; ++j) v[j] = c[j];
    } else if (c0 == 192) {  // cfg 17 | zeros
      v[0] = sC[r * 18 + 17];
#pragma unroll
      for (int j = 1; j < 8; ++j) v[j] = 0.f;
    } else {
#pragma unroll
      for (int j = 0; j < 8; ++j) v[j] = 0.f;
    }
    half8 o;
#pragma unroll
    for (int j = 0; j < 8; ++j) o[j] = (_Float16)v[j];
    *(half8*)(Out + (size_t)(base + r) * 224 + c0) = o;
  }
}

// ---------------- MFMA GEMM, B staged in LDS ----------------
// Out[r,:] = epi( A0[r]@W0 (+ A1[r]@W1) + bias ), A f16 row-major pitch K, W f16
// transposed (NC x K). MODE 0 = relu, 1 = row L2-normalize.
// 256 thr = 4 waves; 64 rows/wave (4 row-tiles), 256 rows/block.
template <int K0, int K1, int NC, int MODE>
__global__ __launch_bounds__(256) void k_mm(
    const _Float16* __restrict__ A0, const _Float16* __restrict__ W0,
    const _Float16* __restrict__ A1, const _Float16* __restrict__ W1,
    const float* __restrict__ bias, _Float16* __restrict__ Out, int N) {
  constexpr int NT = NC / 16;  // col tiles
  constexpr int RT = 4;        // row tiles per wave
  constexpr int KP0 = K0 + 8;  // padded LDS pitch (f16)
  constexpr int KP1 = K1 + 8;
  __shared__ _Float16 sB0[NC * KP0];
  __shared__ _Float16 sB1[(K1 > 0) ? (NC * KP1) : 8];

  for (int idx = threadIdx.x; idx < NC * (K0 / 8); idx += 256) {
    int nn = idx / (K0 / 8), k8 = idx - nn * (K0 / 8);
    *(half8*)(sB0 + nn * KP0 + k8 * 8) = *(const half8*)(W0 + (size_t)nn * K0 + k8 * 8);
  }
  if constexpr (K1 > 0) {
    for (int idx = threadIdx.x; idx < NC * (K1 / 8); idx += 256) {
      int nn = idx / (K1 / 8), k8 = idx - nn * (K1 / 8);
      *(half8*)(sB1 + nn * KP1 + k8 * 8) = *(const half8*)(W1 + (size_t)nn * K1 + k8 * 8);
    }
  }
  __syncthreads();

  const int lane = threadIdx.x & 63, wave = threadIdx.x >> 6;
  const int quad = lane >> 4, l15 = lane & 15;
  const int r0 = blockIdx.x * 256 + wave * 64;

  f32x4 acc[RT][NT];
#pragma unroll
  for (int rt = 0; rt < RT; ++rt)
#pragma unroll
    for (int t = 0; t < NT; ++t) acc[rt][t] = (f32x4)0.f;

  {
    const _Float16* ap = A0 + (size_t)(r0 + l15) * K0 + quad * 8;
#pragma unroll
    for (int k = 0; k < K0; k += 32) {
      half8 a[RT];
#pragma unroll
      for (int rt = 0; rt < RT; ++rt) a[rt] = *(const half8*)(ap + (size_t)rt * 16 * K0 + k);
#pragma unroll
      for (int t = 0; t < NT; ++t) {
        half8 b = *(const half8*)(sB0 + (t * 16 + l15) * KP0 + quad * 8 + k);
#pragma unroll
        for (int rt = 0; rt < RT; ++rt)
          acc[rt][t] = __builtin_amdgcn_mfma_f32_16x16x32_f16(a[rt], b, acc[rt][t], 0, 0, 0);
      }
    }
  }
  if constexpr (K1 > 0) {
    const _Float16* ap = A1 + (size_t)(r0 + l15) * K1 + quad * 8;
#pragma unroll
    for (int k = 0; k < K1; k += 32) {
      half8 a[RT];
#pragma unroll
      for (int rt = 0; rt < RT; ++rt) a[rt] = *(const half8*)(ap + (size_t)rt * 16 * K1 + k);
#pragma unroll
      for (int t = 0; t < NT; ++t) {
        half8 b = *(const half8*)(sB1 + (t * 16 + l15) * KP1 + quad * 8 + k);
#pragma unroll
        for (int rt = 0; rt < RT; ++rt)
          acc[rt][t] = __builtin_amdgcn_mfma_f32_16x16x32_f16(a[rt], b, acc[rt][t], 0, 0, 0);
      }
    }
  }

#pragma unroll
  for (int rt = 0; rt < RT; ++rt) {
#pragma unroll
    for (int t = 0; t < NT; ++t) {
      float bv = bias[t * 16 + l15];
      acc[rt][t][0] += bv; acc[rt][t][1] += bv;
      acc[rt][t][2] += bv; acc[rt][t][3] += bv;
    }
    if constexpr (MODE == 1) {
      f32x4 ss = (f32x4)0.f;
#pragma unroll
      for (int t = 0; t < NT; ++t) ss += acc[rt][t] * acc[rt][t];
#pragma unroll
      for (int j = 0; j < 4; ++j) {
        float s = ss[j];
        s += __shfl_xor(s, 1);
        s += __shfl_xor(s, 2);
        s += __shfl_xor(s, 4);
        s += __shfl_xor(s, 8);
        float sc = 1.f / fmaxf(sqrtf(s), 1e-12f);
#pragma unroll
        for (int t = 0; t < NT; ++t) acc[rt][t][j] *= sc;
      }
    } else {
#pragma unroll
      for (int t = 0; t < NT; ++t) {
        acc[rt][t][0] = fmaxf(acc[rt][t][0], 0.f);
        acc[rt][t][1] = fmaxf(acc[rt][t][1], 0.f);
        acc[rt][t][2] = fmaxf(acc[rt][t][2], 0.f);
        acc[rt][t][3] = fmaxf(acc[rt][t][3], 0.f);
      }
    }
#pragma unroll
    for (int j = 0; j < 4; ++j) {
      int r = r0 + rt * 16 + quad * 4 + j;
      if (r < N) {
#pragma unroll
        for (int t = 0; t < NT; ++t)
          Out[(size_t)r * NC + t * 16 + l15] = (_Float16)acc[rt][t][j];
      }
    }
  }
}

// ---------------- CSR mean aggregation (f16, fp32 acc), 8B/lane + 4x edge unroll ----
template <int NC>
__global__ __launch_bounds__(256) void k_agg(const _Float16* __restrict__ xp,
                                             const int* __restrict__ offs,
                                             const int* __restrict__ esrc,
                                             const float* __restrict__ deginv,
                                             _Float16* __restrict__ agg, int N) {
  constexpr int LPN = NC / 4;  // lanes per node, 4 f16 (8B) per lane
  int t = blockIdx.x * 256 + threadIdx.x;
  int node = t / LPN;
  int lane = t - node * LPN;
  if (node >= N) return;
  int s0 = offs[node], s1 = offs[node + 1];
  float a0 = 0.f, a1 = 0.f, a2 = 0.f, a3 = 0.f;
  for (int i = s0; i < s1; i += 4) {
    int nlast = s1 - 1;
    int e0 = esrc[i];
    int e1 = esrc[min(i + 1, nlast)];
    int e2 = esrc[min(i + 2, nlast)];
    int e3 = esrc[min(i + 3, nlast)];
    h4 v0 = ((const h4*)(xp + (size_t)e0 * NC))[lane];
    h4 v1 = ((const h4*)(xp + (size_t)e1 * NC))[lane];
    h4 v2 = ((const h4*)(xp + (size_t)e2 * NC))[lane];
    h4 v3 = ((const h4*)(xp + (size_t)e3 * NC))[lane];
    a0 += (float)v0[0]; a1 += (float)v0[1]; a2 += (float)v0[2]; a3 += (float)v0[3];
    if (i + 1 < s1) { a0 += (float)v1[0]; a1 += (float)v1[1]; a2 += (float)v1[2]; a3 += (float)v1[3]; }
    if (i + 2 < s1) { a0 += (float)v2[0]; a1 += (float)v2[1]; a2 += (float)v2[2]; a3 += (float)v2[3]; }
    if (i + 3 < s1) { a0 += (float)v3[0]; a1 += (float)v3[1]; a2 += (float)v3[2]; a3 += (float)v3[3]; }
  }
  float di = deginv[node];
  h4 o;
  o[0] = (_Float16)(a0 * di); o[1] = (_Float16)(a1 * di);
  o[2] = (_Float16)(a2 * di); o[3] = (_Float16)(a3 * di);
  ((h4*)(agg + (size_t)node * NC))[lane] = o;
}

// ---------------- pooling ----------------
__global__ __launch_bounds__(256) void k_pool1(const _Float16* __restrict__ x,
                                               const int* __restrict__ batch,
                                               unsigned* __restrict__ gkey,
                                               float* __restrict__ gsum,
                                               int* __restrict__ gcnt, int N) {
  int chunk = blockIdx.x * 4 + (threadIdx.x >> 6);
  int lane = threadIdx.x & 63;
  int n0 = chunk * 64;
  if (n0 >= N) return;
  int n1 = min(n0 + 64, N);
  float rmax = -3.4e38f, rsum = 0.f;
  int rcnt = 0, curb = batch[n0];
  for (int n = n0; n < n1; ++n) {
    int b = batch[n];
    if (b != curb) {
      atomicMax(&gkey[curb * 64 + lane], fkey(rmax));
      atomicAdd(&gsum[curb * 64 + lane], rsum);
      if (lane == 0) atomicAdd(&gcnt[curb], rcnt);
      rmax = -3.4e38f; rsum = 0.f; rcnt = 0; curb = b;
    }
    float v = (float)x[(size_t)n * 64 + lane];
    rmax = fmaxf(rmax, v);
    rsum += v;
    rcnt++;
  }
  atomicMax(&gkey[curb * 64 + lane], fkey(rmax));
  atomicAdd(&gsum[curb * 64 + lane], rsum);
  if (lane == 0) atomicAdd(&gcnt[curb], rcnt);
}

__global__ __launch_bounds__(1024) void k_pool2(const unsigned* __restrict__ gkey,
                                                const float* __restrict__ gsum,
                                                const int* __restrict__ gcnt,
                                                const float* __restrict__ post_w,
                                                const float* __restrict__ post_b,
                                                float* __restrict__ out) {
  int b = threadIdx.x >> 6, lane = threadIdx.x & 63;
  float m = funkey(gkey[b * 64 + lane]);
  float s = gsum[b * 64 + lane];
  float c = (float)gcnt[b];
  float g = m + s / fmaxf(c, 1.f);
  float ss = g * g;
#pragma unroll
  for (int off = 1; off < 64; off <<= 1) ss += __shfl_xor(ss, off);
  float gn = g / fmaxf(sqrtf(ss), 1e-30f);
  float contrib = gn * post_w[lane];
#pragma unroll
  for (int off = 1; off < 64; off <<= 1) contrib += __shfl_xor(contrib, off);
  if (lane == 0) out[b] = contrib + post_b[0];
}

extern "C" void kernel_launch(void* const* d_in, const int* in_sizes, int n_in,
                              void* d_out, int out_size, void* d_ws, size_t ws_size,
                              hipStream_t stream) {
  const float* node_feat = (const float*)d_in[0];
  const float* cfgf      = (const float*)d_in[1];
  const int*   opcode    = (const int*)d_in[2];
  const int*   eidx      = (const int*)d_in[3];
  const int*   batch     = (const int*)d_in[4];
  const float* op_emb    = (const float*)d_in[5];
  const float* type_emb  = (const float*)d_in[6];
  const float* lin_w     = (const float*)d_in[7];
  const float* lin_b     = (const float*)d_in[8];
  const float* post_w    = (const float*)d_in[9];
  const float* post_b    = (const float*)d_in[10];
  const float* wp[3] = {(const float*)d_in[11], (const float*)d_in[16], (const float*)d_in[21]};
  const float* bp[3] = {(const float*)d_in[12], (const float*)d_in[17], (const float*)d_in[22]};
  const float* wl[3] = {(const float*)d_in[13], (const float*)d_in[18], (const float*)d_in[23]};
  const float* bl[3] = {(const float*)d_in[14], (const float*)d_in[19], (const float*)d_in[24]};
  const float* wr[3] = {(const float*)d_in[15], (const float*)d_in[20], (const float*)d_in[25]};

  const int N = in_sizes[2];
  const int E = in_sizes[3] / 2;
  const int NPAD = ((N + 255) / 256) * 256;
  const int* e_src = eidx;
  const int* e_dst = eidx + E;

  char* p = (char*)d_ws;
  auto alloc = [&](size_t bytes) -> void* {
    void* r = (void*)p;
    p += (bytes + 255) & ~(size_t)255;
    return r;
  };
  _Float16* F  = (_Float16*)alloc((size_t)NPAD * 224 * 2);
  _Float16* X1 = (_Float16*)alloc((size_t)NPAD * 128 * 2);
  _Float16* R2 = (_Float16*)alloc((size_t)NPAD * 128 * 2);
  _Float16* R3 = (_Float16*)alloc((size_t)NPAD * 128 * 2);
  _Float16* WT = (_Float16*)alloc(86016 * 2);
  int* counts    = (int*)alloc((size_t)N * 4);
  int* offsets   = (int*)alloc((size_t)(N + 1) * 4);
  int* fillpos   = (int*)alloc((size_t)N * 4);
  float* deginv  = (float*)alloc((size_t)N * 4);
  int* blockSums = (int*)alloc(1024 * 4);
  int* esrc      = (int*)alloc((size_t)E * 4);
  unsigned* gkey = (unsigned*)alloc(16 * 64 * 4);
  float* gsum    = (float*)alloc(16 * 64 * 4);
  int* gcnt      = (int*)alloc(16 * 4);
  (void)ws_size; (void)n_in; (void)out_size;

  _Float16* WTenc = WT + 0;       // 128 x 224
  _Float16* WTp0  = WT + 28672;   // 128 x 128
  _Float16* WTl0  = WT + 45056;   // 64 x 128
  _Float16* WTr0  = WT + 53248;   // 64 x 128
  _Float16* WTp1  = WT + 61440;   // 64 x 64
  _Float16* WTl1  = WT + 65536;
  _Float16* WTr1  = WT + 69632;
  _Float16* WTp2  = WT + 73728;
  _Float16* WTl2  = WT + 77824;
  _Float16* WTr2  = WT + 81920;

  WDs wds;
  wds.d[0] = {lin_w, WTenc, 193, 128, 224, 0};
  wds.d[1] = {wp[0], WTp0, 128, 128, 128, 28672};
  wds.d[2] = {wl[0], WTl0, 128, 64, 128, 45056};
  wds.d[3] = {wr[0], WTr0, 128, 64, 128, 53248};
  wds.d[4] = {wp[1], WTp1, 64, 64, 64, 61440};
  wds.d[5] = {wl[1], WTl1, 64, 64, 64, 65536};
  wds.d[6] = {wr[1], WTr1, 64, 64, 64, 69632};
  wds.d[7] = {wp[2], WTp2, 64, 64, 64, 73728};
  wds.d[8] = {wl[2], WTl2, 64, 64, 64, 77824};
  wds.d[9] = {wr[2], WTr2, 64, 64, 64, 81920};
  wds.total = 86016;

  hipMemsetAsync(counts, 0, (size_t)N * 4, stream);
  hipMemsetAsync(gkey, 0, 16 * 64 * 4, stream);
  hipMemsetAsync(gsum, 0, 16 * 64 * 4, stream);
  hipMemsetAsync(gcnt, 0, 16 * 4, stream);

  const int nbE = (E + 255) / 256;
  const int nbN = (N + 255) / 256;
  const int nbMM = NPAD / 256;
  const int nbA128 = ((size_t)N * 32 + 255) / 256;
  const int nbA64  = ((size_t)N * 16 + 255) / 256;
  const int nbP = ((N + 63) / 64 + 3) / 4;

  k_wconv<<<(86016 + 255) / 256, 256, 0, stream>>>(wds);
  k_count<<<nbE, 256, 0, stream>>>(e_dst, counts, E);
  k_scan1<<<nbN, 256, 0, stream>>>(counts, offsets, blockSums, N);
  k_scan2<<<1, 1024, 0, stream>>>(blockSums, nbN);
  k_scan3<<<nbN, 256, 0, stream>>>(counts, offsets, blockSums, fillpos, deginv, N, E);
  k_fill<<<nbE, 256, 0, stream>>>(e_src, e_dst, fillpos, esrc, E);

  k_feat<<<(N + 63) / 64, 256, 0, stream>>>(node_feat, cfgf, opcode, op_emb, type_emb, F, N);
  // encode: relu(F @ Wenc + lin_b) -> X1 (N x 128)
  k_mm<224, 0, 128, 0><<<nbMM, 256, 0, stream>>>(F, WTenc, nullptr, nullptr, lin_b, X1, N);

  // ---- layer 0 ----
  k_mm<128, 0, 128, 0><<<nbMM, 256, 0, stream>>>(X1, WTp0, nullptr, nullptr, bp[0], R2, N);
  k_agg<128><<<nbA128, 256, 0, stream>>>(R2, offsets, esrc, deginv, R3, N);
  k_mm<128, 128, 64, 1><<<nbMM, 256, 0, stream>>>(R3, WTl0, X1, WTr0, bl[0], R2, N);
  // ---- layer 1 ----
  k_mm<64, 0, 64, 0><<<nbMM, 256, 0, stream>>>(R2, WTp1, nullptr, nullptr, bp[1], R3, N);
  k_agg<64><<<nbA64, 256, 0, stream>>>(R3, offsets, esrc, deginv, X1, N);
  k_mm<64, 64, 64, 1><<<nbMM, 256, 0, stream>>>(X1, WTl1, R2, WTr1, bl[1], R3, N);
  // ---- layer 2 ----
  k_mm<64, 0, 64, 0><<<nbMM, 256, 0, stream>>>(R3, WTp2, nullptr, nullptr, bp[2], X1, N);
  k_agg<64><<<nbA64, 256, 0, stream>>>(X1, offsets, esrc, deginv, R2, N);
  k_mm<64, 64, 64, 1><<<nbMM, 256, 0, stream>>>(R2, WTl2, R3, WTr2, bl[2], X1, N);

  // pooling -> out (B=16)
  k_pool1<<<nbP, 256, 0, stream>>>(X1, batch, gkey, gsum, gcnt, N);
  k_pool2<<<1, 1024, 0, stream>>>(gkey, gsum, gcnt, post_w, post_b, (float*)d_out);
}